// Round 6
// baseline (39.423 us; speedup 1.0000x reference)
//
#include <hip/hip_runtime.h>
#include <math.h>

#define NF 1024
#define IMS 256
#define TILE 8
#define NT 1024
#define BT 512              // raster block threads (8 waves)
constexpr float SIGMA = 0.003f;
constexpr float LOG2E = 1.4426950408889634f;
constexpr float PXSZ = 2.0f / (float)IMS;
constexpr float TILE_R = 3.5f * PXSZ;   // max |pixel-center - tile-center|

#if __has_builtin(__builtin_amdgcn_exp2f)
#define EXP2(x) __builtin_amdgcn_exp2f(x)
#else
#define EXP2(x) exp2f(x)
#endif

// ---- prep: per-face projection + edge coefficients (math verbatim from r4) ----
__global__ __launch_bounds__(256) void prep_kernel(const float* __restrict__ verts,
                                                   const int* __restrict__ faces,
                                                   float* __restrict__ coef,
                                                   int* __restrict__ counter) {
    int f = blockIdx.x * 256 + threadIdx.x;
    if (f == 0) *counter = 0;
    if (f >= NF) return;

    const float deg2rad = 0.017453292519943295f;
    float e = 0.0f * deg2rad, a = 90.0f * deg2rad;
    float ce = cosf(e), se = sinf(e), ca = cosf(a), sa = sinf(a);
    float ex = 2.732f * ce * sa, ey = 2.732f * se, ez = -2.732f * ce * ca;
    float zn = sqrtf(ex*ex + ey*ey + ez*ez) + 1e-12f;
    float zx = -ex/zn, zy = -ey/zn, zz = -ez/zn;
    float cx = 1.0f*zz, cyv = 0.0f, cz = -1.0f*zx;   // cross(up, zax), up=(0,1,0)
    float xn = sqrtf(cx*cx + cyv*cyv + cz*cz) + 1e-12f;
    float xax_x = cx/xn, xax_y = cyv/xn, xax_z = cz/xn;
    float yx = zy*xax_z - zz*xax_y;
    float yy = zz*xax_x - zx*xax_z;
    float yz = zx*xax_y - zy*xax_x;
    float w = tanf(30.0f * deg2rad);

    int i0 = faces[f*3+0], i1 = faces[f*3+1], i2 = faces[f*3+2];
    float P[3][2];
    int idx[3] = {i0, i1, i2};
    #pragma unroll
    for (int k = 0; k < 3; ++k) {
        float vx = verts[idx[k]*3+0] - ex;
        float vy = verts[idx[k]*3+1] - ey;
        float vz = verts[idx[k]*3+2] - ez;
        float camx = xax_x*vx + xax_y*vy + xax_z*vz;
        float camy = yx*vx + yy*vy + yz*vz;
        float camz = zx*vx + zy*vy + zz*vz;
        float z = fmaxf(camz, 0.01f);
        float invzw = 1.0f / (z * w);
        P[k][0] = camx * invzw;
        P[k][1] = camy * invzw;
    }
    float area = (P[1][0]-P[0][0])*(P[2][1]-P[0][1]) - (P[1][1]-P[0][1])*(P[2][0]-P[0][0]);
    float s = (area >= 0.0f) ? 1.0f : -1.0f;
    float o[9];
    #pragma unroll
    for (int k = 0; k < 3; ++k) {
        float x0 = P[k][0],       y0 = P[k][1];
        float x1 = P[(k+1)%3][0], y1 = P[(k+1)%3][1];
        float ex_ = x1 - x0, ey_ = y1 - y0;
        float len = sqrtf(ex_*ex_ + ey_*ey_);
        float inv = s * (LOG2E / SIGMA) / (len + 1e-12f);
        o[k*3+0] = -ey_ * inv;
        o[k*3+1] =  ex_ * inv;
        o[k*3+2] = (ey_*x0 - ex_*y0) * inv;
    }
    float* dst = coef + f*12;
    #pragma unroll
    for (int k = 0; k < 9; ++k) dst[k] = o[k];
    dst[9] = dst[10] = dst[11] = 0.0f;
}

// ---- raster: bin (cov-break) + LDS stage + compute + last-block loss reduce ----
__global__ __launch_bounds__(BT) void raster_kernel(const float* __restrict__ coef,
                                                    const float* __restrict__ img,
                                                    float* __restrict__ partials,
                                                    int* __restrict__ counter,
                                                    float* __restrict__ out) {
    __shared__ float4 scoef[BT * 3];       // 24 KB staged coefs
    __shared__ unsigned short slist[NF];   // 2 KB survivor list
    __shared__ float part[8][64];          // 2 KB wave partial products
    __shared__ int cnt, cov, last;
    int t = threadIdx.x;
    int tile = blockIdx.x;
    int ti = tile >> 5, tj = tile & 31;
    if (t == 0) { cnt = 0; cov = 0; }
    __syncthreads();

    const float4* c4 = (const float4*)coef;
    float cxn = ((float)(tj * TILE) + 4.0f) * PXSZ - 1.0f;
    float cyn = -(((float)(ti * TILE) + 4.0f) * PXSZ - 1.0f);

    // ---- bin: 2 rounds of 512; break as soon as tile is known covered ----
    #pragma unroll
    for (int k = 0; k < NF / BT; ++k) {
        int f = t + BT * k;
        float4 c0 = c4[f*3+0];
        float4 c1 = c4[f*3+1];
        float4 c2 = c4[f*3+2];
        float d0 = fmaf(c0.x, cxn, fmaf(c0.y, cyn, c0.z));
        float r0 = (fabsf(c0.x) + fabsf(c0.y)) * TILE_R;
        float d1 = fmaf(c0.w, cxn, fmaf(c1.x, cyn, c1.y));
        float r1 = (fabsf(c0.w) + fabsf(c1.x)) * TILE_R;
        float d2 = fmaf(c1.z, cxn, fmaf(c1.w, cyn, c2.x));
        float r2 = (fabsf(c1.z) + fabsf(c1.w)) * TILE_R;
        float t_hi = fminf(d0 + r0, fminf(d1 + r1, d2 + r2));
        float t_lo = fminf(d0 - r0, fminf(d1 - r1, d2 - r2));
        if (t_lo > 130.0f) atomicOr(&cov, 1);            // factor exactly 0 tile-wide
        else if (t_hi > -26.0f) {                         // factor != 1 somewhere in tile
            int pos = atomicAdd(&cnt, 1);
            slist[pos] = (unsigned short)f;
        }
        __syncthreads();
        if (cov) break;                                   // uniform after barrier
    }

    // ---- compute: survivors strided across 8 waves, coefs from LDS broadcast ----
    int lane = t & 63, wave = t >> 6;
    int pi = ti * TILE + (lane >> 3);
    int pj = tj * TILE + (lane & 7);
    float px = ((float)pj + 0.5f) * PXSZ - 1.0f;
    float py = -(((float)pi + 0.5f) * PXSZ - 1.0f);
    float prod = 1.0f;
    int covered = cov;   // uniform
    if (!covered) {
        int len = cnt;
        bool alive = true;
        for (int base = 0; base < len; base += BT) {
            int m = min(BT, len - base);
            if (t < m) {
                int f = (int)slist[base + t];
                scoef[t*3+0] = c4[f*3+0];
                scoef[t*3+1] = c4[f*3+1];
                scoef[t*3+2] = c4[f*3+2];
            }
            __syncthreads();
            if (alive) {
                int it = 0;
                for (int j = wave; j < m; j += 8) {
                    float4 c0 = scoef[j*3+0];    // LDS broadcast
                    float4 c1 = scoef[j*3+1];
                    float4 c2 = scoef[j*3+2];
                    float d0 = fmaf(c0.x, px, fmaf(c0.y, py, c0.z));
                    float d1 = fmaf(c0.w, px, fmaf(c1.x, py, c1.y));
                    float d2 = fmaf(c1.z, px, fmaf(c1.w, py, c2.x));
                    float tm = fminf(d0, fminf(d1, d2));
                    float ef = EXP2(tm);                          // overflow -> inf
                    prod *= __builtin_amdgcn_rcpf(1.0f + ef);     // rcp(inf) -> 0
                    if ((++it & 7) == 0 && __ballot(prod > 0.0f) == 0ull) { alive = false; break; }
                }
            }
            __syncthreads();
        }
    }
    part[wave][lane] = prod;
    __syncthreads();

    // ---- per-block loss partial (wave 0) ----
    float v = 0.0f;
    if (t < 64) {
        float pr = covered ? 0.0f
                 : part[0][t]*part[1][t]*part[2][t]*part[3][t]
                 * part[4][t]*part[5][t]*part[6][t]*part[7][t];
        float sil = 1.0f - pr;
        float diff = sil - img[pi * IMS + pj];
        v = diff * diff;
        #pragma unroll
        for (int o = 32; o > 0; o >>= 1) v += __shfl_down(v, o);
    }
    if (t == 0) {
        __hip_atomic_store(&partials[tile], v, __ATOMIC_RELEASE, __HIP_MEMORY_SCOPE_AGENT);
        __threadfence();
        int old = atomicAdd(counter, 1);     // device-scope
        last = (old == NT - 1) ? 1 : 0;
    }
    __syncthreads();

    // ---- last block: deterministic fixed-order sum of all 1024 partials ----
    if (last) {
        __threadfence();
        float s = 0.0f;
        #pragma unroll
        for (int i = 0; i < NT / BT; ++i)
            s += __hip_atomic_load(&partials[t + i * BT], __ATOMIC_RELAXED, __HIP_MEMORY_SCOPE_AGENT);
        #pragma unroll
        for (int o = 32; o > 0; o >>= 1) s += __shfl_down(s, o);
        __shared__ float red[8];
        if ((t & 63) == 0) red[t >> 6] = s;
        __syncthreads();
        if (t == 0) {
            float tot = 0.0f;
            #pragma unroll
            for (int wv = 0; wv < 8; ++wv) tot += red[wv];
            out[0] = tot;
        }
    }
}

extern "C" void kernel_launch(void* const* d_in, const int* in_sizes, int n_in,
                              void* d_out, int out_size, void* d_ws, size_t ws_size,
                              hipStream_t stream) {
    const float* verts = (const float*)d_in[0];
    const float* img   = (const float*)d_in[1];
    const int*   faces = (const int*)d_in[2];
    float* out = (float*)d_out;
    char* ws = (char*)d_ws;
    float* coef     = (float*)ws;               // 48 KB
    float* partials = (float*)(ws + 49152);     // 4 KB
    int*   counter  = (int*)(ws + 49152 + 4096);

    prep_kernel<<<4, 256, 0, stream>>>(verts, faces, coef, counter);
    raster_kernel<<<NT, BT, 0, stream>>>(coef, img, partials, counter, out);
}

// Round 7
// 29.287 us; speedup vs baseline: 1.3461x; 1.3461x over previous
//
#include <hip/hip_runtime.h>
#include <math.h>

#define NF 1024
#define IMS 256
#define TILE 8
#define NT 1024
#define CHUNK 256         // faces staged in LDS per round
#define NSLOT 64          // spread accumulator slots (64B apart)
#define SLOTSTRIDE 16     // floats between slots
constexpr float SIGMA = 0.003f;
constexpr float LOG2E = 1.4426950408889634f;
constexpr float PXSZ = 2.0f / (float)IMS;
constexpr float TILE_R = 3.5f * PXSZ;   // max |pixel-center - tile-center|

#if __has_builtin(__builtin_amdgcn_exp2f)
#define EXP2(x) __builtin_amdgcn_exp2f(x)
#else
#define EXP2(x) exp2f(x)
#endif

// ---- prep: per-face projection + edge coefficients (math verbatim from r4) ----
// Also zeroes the 64 spread accumulator slots (replaces the memset node).
__global__ __launch_bounds__(256) void prep_kernel(const float* __restrict__ verts,
                                                   const int* __restrict__ faces,
                                                   float* __restrict__ coef,
                                                   float* __restrict__ partials) {
    int f = blockIdx.x * 256 + threadIdx.x;
    if (blockIdx.x == 0 && threadIdx.x < NSLOT) partials[threadIdx.x * SLOTSTRIDE] = 0.0f;
    if (f >= NF) return;

    const float deg2rad = 0.017453292519943295f;
    float e = 0.0f * deg2rad, a = 90.0f * deg2rad;
    float ce = cosf(e), se = sinf(e), ca = cosf(a), sa = sinf(a);
    float ex = 2.732f * ce * sa, ey = 2.732f * se, ez = -2.732f * ce * ca;
    float zn = sqrtf(ex*ex + ey*ey + ez*ez) + 1e-12f;
    float zx = -ex/zn, zy = -ey/zn, zz = -ez/zn;
    float cx = 1.0f*zz, cyv = 0.0f, cz = -1.0f*zx;   // cross(up, zax), up=(0,1,0)
    float xn = sqrtf(cx*cx + cyv*cyv + cz*cz) + 1e-12f;
    float xax_x = cx/xn, xax_y = cyv/xn, xax_z = cz/xn;
    float yx = zy*xax_z - zz*xax_y;
    float yy = zz*xax_x - zx*xax_z;
    float yz = zx*xax_y - zy*xax_x;
    float w = tanf(30.0f * deg2rad);

    int i0 = faces[f*3+0], i1 = faces[f*3+1], i2 = faces[f*3+2];
    float P[3][2];
    int idx[3] = {i0, i1, i2};
    #pragma unroll
    for (int k = 0; k < 3; ++k) {
        float vx = verts[idx[k]*3+0] - ex;
        float vy = verts[idx[k]*3+1] - ey;
        float vz = verts[idx[k]*3+2] - ez;
        float camx = xax_x*vx + xax_y*vy + xax_z*vz;
        float camy = yx*vx + yy*vy + yz*vz;
        float camz = zx*vx + zy*vy + zz*vz;
        float z = fmaxf(camz, 0.01f);
        float invzw = 1.0f / (z * w);
        P[k][0] = camx * invzw;
        P[k][1] = camy * invzw;
    }
    float area = (P[1][0]-P[0][0])*(P[2][1]-P[0][1]) - (P[1][1]-P[0][1])*(P[2][0]-P[0][0]);
    float s = (area >= 0.0f) ? 1.0f : -1.0f;
    float o[9];
    #pragma unroll
    for (int k = 0; k < 3; ++k) {
        float x0 = P[k][0],       y0 = P[k][1];
        float x1 = P[(k+1)%3][0], y1 = P[(k+1)%3][1];
        float ex_ = x1 - x0, ey_ = y1 - y0;
        float len = sqrtf(ex_*ex_ + ey_*ey_);
        float inv = s * (LOG2E / SIGMA) / (len + 1e-12f);
        o[k*3+0] = -ey_ * inv;
        o[k*3+1] =  ex_ * inv;
        o[k*3+2] = (ey_*x0 - ex_*y0) * inv;
    }
    float* dst = coef + f*12;
    #pragma unroll
    for (int k = 0; k < 9; ++k) dst[k] = o[k];
    dst[9] = dst[10] = dst[11] = 0.0f;
}

// ---- raster: bin + stage + compute (verbatim r4) + slot-spread loss tail ----
__global__ __launch_bounds__(256) void raster_kernel(const float* __restrict__ coef,
                                                     const float* __restrict__ img,
                                                     float* __restrict__ partials) {
    __shared__ unsigned short slist[NF];   // 2 KB
    __shared__ float4 scoef[CHUNK * 3];    // 12 KB
    __shared__ float part[4][64];          // 1 KB
    __shared__ int cnt, cov, done;
    int t = threadIdx.x;
    int tile = blockIdx.x;
    int ti = tile >> 5, tj = tile & 31;
    if (t == 0) { cnt = 0; cov = 0; done = 0; }
    __syncthreads();

    const float4* c4 = (const float4*)coef;
    // ---- bin: cull faces vs this tile (4 rounds x 256 threads) ----
    float cxn = ((float)(tj * TILE) + 4.0f) * PXSZ - 1.0f;
    float cyn = -(((float)(ti * TILE) + 4.0f) * PXSZ - 1.0f);
    #pragma unroll
    for (int k = 0; k < NF / 256; ++k) {
        int f = t + 256 * k;
        float4 c0 = c4[f*3+0];
        float4 c1 = c4[f*3+1];
        float4 c2 = c4[f*3+2];
        float d0 = fmaf(c0.x, cxn, fmaf(c0.y, cyn, c0.z));
        float r0 = (fabsf(c0.x) + fabsf(c0.y)) * TILE_R;
        float d1 = fmaf(c0.w, cxn, fmaf(c1.x, cyn, c1.y));
        float r1 = (fabsf(c0.w) + fabsf(c1.x)) * TILE_R;
        float d2 = fmaf(c1.z, cxn, fmaf(c1.w, cyn, c2.x));
        float r2 = (fabsf(c1.z) + fabsf(c1.w)) * TILE_R;
        float t_hi = fminf(d0 + r0, fminf(d1 + r1, d2 + r2));
        float t_lo = fminf(d0 - r0, fminf(d1 - r1, d2 - r2));
        if (t_lo > 130.0f) atomicOr(&cov, 1);            // factor exactly 0 tile-wide
        else if (t_hi > -26.0f) {                         // factor != 1 somewhere in tile
            int pos = atomicAdd(&cnt, 1);
            slist[pos] = (unsigned short)f;
        }
    }
    __syncthreads();

    int lane = t & 63, wave = t >> 6;
    int pi = ti * TILE + (lane >> 3);
    int pj = tj * TILE + (lane & 7);
    float px = ((float)pj + 0.5f) * PXSZ - 1.0f;
    float py = -(((float)pi + 0.5f) * PXSZ - 1.0f);
    float prod = 1.0f;
    int covered = cov;   // uniform after barrier
    if (!covered) {
        int len = cnt;
        for (int base = 0; base < len; base += CHUNK) {
            int m = min(CHUNK, len - base);
            // parallel gather of surviving faces' coefs into LDS
            if (t < m) {
                int f = (int)slist[base + t];
                scoef[t*3+0] = c4[f*3+0];
                scoef[t*3+1] = c4[f*3+1];
                scoef[t*3+2] = c4[f*3+2];
            }
            __syncthreads();
            // each wave covers all 64 pixels; faces strided across 4 waves
            int it = 0;
            for (int j = wave; j < m; j += 4) {
                float4 c0 = scoef[j*3+0];    // LDS broadcast (same addr all lanes)
                float4 c1 = scoef[j*3+1];
                float4 c2 = scoef[j*3+2];
                float d0 = fmaf(c0.x, px, fmaf(c0.y, py, c0.z));
                float d1 = fmaf(c0.w, px, fmaf(c1.x, py, c1.y));
                float d2 = fmaf(c1.z, px, fmaf(c1.w, py, c2.x));
                float tm = fminf(d0, fminf(d1, d2));
                float ef = EXP2(tm);                          // overflow -> inf
                prod *= __builtin_amdgcn_rcpf(1.0f + ef);     // rcp(inf) -> 0
                if ((++it & 7) == 0 && __ballot(prod > 0.0f) == 0ull) {
                    atomicOr(&done, 1);   // my partial is 0 for all 64 pixels -> final is 0
                    break;
                }
            }
            __syncthreads();              // all waves finished reading scoef
            if (done) break;              // uniform after barrier
        }
    }
    part[wave][lane] = prod;
    __syncthreads();

    if (wave == 0) {
        float pr = covered ? 0.0f
                 : part[0][lane] * part[1][lane] * part[2][lane] * part[3][lane];
        float sil = 1.0f - pr;
        float diff = sil - img[pi * IMS + pj];
        float v = diff * diff;
        #pragma unroll
        for (int o = 32; o > 0; o >>= 1) v += __shfl_down(v, o);
        // spread the tail: 16 blocks per slot, slots on distinct 64B lines
        if (lane == 0) atomicAdd(&partials[(tile & (NSLOT-1)) * SLOTSTRIDE], v);
    }
}

// ---- final: deterministic sum of the 64 slots ----
__global__ __launch_bounds__(64) void reduce_kernel(const float* __restrict__ partials,
                                                    float* __restrict__ out) {
    float v = partials[threadIdx.x * SLOTSTRIDE];
    #pragma unroll
    for (int o = 32; o > 0; o >>= 1) v += __shfl_down(v, o);
    if (threadIdx.x == 0) out[0] = v;
}

extern "C" void kernel_launch(void* const* d_in, const int* in_sizes, int n_in,
                              void* d_out, int out_size, void* d_ws, size_t ws_size,
                              hipStream_t stream) {
    const float* verts = (const float*)d_in[0];
    const float* img   = (const float*)d_in[1];
    const int*   faces = (const int*)d_in[2];
    float* out = (float*)d_out;
    char* ws = (char*)d_ws;
    float* coef     = (float*)ws;               // 48 KB
    float* partials = (float*)(ws + 49152);     // 4 KB (64 slots, 64B apart)

    prep_kernel<<<4, 256, 0, stream>>>(verts, faces, coef, partials);
    raster_kernel<<<NT, 256, 0, stream>>>(coef, img, partials);
    reduce_kernel<<<1, 64, 0, stream>>>(partials, out);
}